// Round 17
// baseline (122.330 us; speedup 1.0000x reference)
//
#include <hip/hip_runtime.h>
#include <hip/hip_bf16.h>
#include <cstdint>
#include <cstddef>

#define NN 10000
#define NE 160000
#define DD 300
#define KP 320      // K padded to 10 MFMA steps of 32
#define NPAD 320    // W rows padded to 20 tiles of 16
#define MTILES 625  // NN/16
#define CAP 64      // bucket capacity per node (max degree ~35 for this graph)
#define GEMMB 256   // gemm blocks inside the fused kernel
#define BUCKB 625   // bucket blocks (625*256 = NE exactly)
#define CONVB 50    // W2-conversion blocks (50*256*8 = NPAD*KP exactly)

using bf16x8 = __attribute__((ext_vector_type(8))) __bf16;
using f32x4  = __attribute__((ext_vector_type(4))) float;
using f32x2  = __attribute__((ext_vector_type(2))) float;

// ---------------- branch-free masked on-the-fly W row -> 10 bf16x8 frags ----------------

__device__ __forceinline__ void load_b_otf(const float* __restrict__ W, int n, int q,
                                           bf16x8* __restrict__ b) {
    const int nc = (n < DD) ? n : 0;
    const float rowm = (n < DD) ? 1.f : 0.f;
    const float* base = W + nc * DD + q * 8;
#pragma unroll
    for (int ks = 0; ks < 10; ++ks) {
        const int k0 = q * 8 + ks * 32;
        f32x4 lo = *(const f32x4*)(base + ks * 32);
        f32x4 hi = *(const f32x4*)(base + ks * 32 + 4);
        bf16x8 bf;
#pragma unroll
        for (int j = 0; j < 4; ++j) {
            const float ml = (k0 + j < DD) ? rowm : 0.f;
            const float mh = (k0 + 4 + j < DD) ? rowm : 0.f;
            bf[j]     = (__bf16)(lo[j] * ml);
            bf[4 + j] = (__bf16)(hi[j] * mh);
        }
        b[ks] = bf;
    }
}

// ---------------- shared GEMM body: G[m][n] = fp8(sum_k A[m][k]*W[n][k]) ----------------

template <bool F32IN, bool OTFW>
__device__ __forceinline__ void gemm_body(int bid, int gstride,
                                          const void* __restrict__ Ap,
                                          const void* __restrict__ Wsrc,
                                          unsigned char* __restrict__ G) {
    const int w = threadIdx.x >> 6;
    const int lane = threadIdx.x & 63;
    const int r = lane & 15;    // A row-in-tile / B col / D col
    const int q = lane >> 4;    // k-block select / D row-block

    bf16x8 b[5][10];
    if constexpr (OTFW) {
        const float* W = (const float*)Wsrc;
#pragma unroll
        for (int t = 0; t < 5; ++t)
            load_b_otf(W, (w * 5 + t) * 16 + r, q, b[t]);
    } else {
        const __bf16* Wb = (const __bf16*)Wsrc;
        const __bf16* Bb = Wb + (size_t)r * KP + q * 8;
#pragma unroll
        for (int t = 0; t < 5; ++t) {
            const __bf16* Bt = Bb + (size_t)(w * 5 + t) * 16 * KP;
#pragma unroll
            for (int ks = 0; ks < 10; ++ks)
                b[t][ks] = *(const bf16x8*)(Bt + ks * 32);
        }
    }

    for (int mt = bid; mt < MTILES; mt += gstride) {
        f32x4 acc[5] = {};
        if constexpr (F32IN) {
            const float* Ab = (const float*)Ap + (size_t)(mt * 16 + r) * DD + q * 8;
#pragma unroll
            for (int ks = 0; ks < 9; ++ks) {   // k0+7 <= 287 < 300: full vectors
                f32x4 lo = *(const f32x4*)(Ab + ks * 32);
                f32x4 hi = *(const f32x4*)(Ab + ks * 32 + 4);
                bf16x8 af;
#pragma unroll
                for (int j = 0; j < 4; ++j) { af[j] = (__bf16)lo[j]; af[4 + j] = (__bf16)hi[j]; }
#pragma unroll
                for (int t = 0; t < 5; ++t)
                    acc[t] = __builtin_amdgcn_mfma_f32_16x16x32_bf16(af, b[t][ks], acc[t], 0, 0, 0);
            }
            {   // ks = 9: k = 288 + q*8 + j, guard k < 300
                bf16x8 af;
#pragma unroll
                for (int j = 0; j < 8; ++j) {
                    int k = 288 + q * 8 + j;
                    af[j] = (__bf16)((k < DD) ? Ab[288 + j] : 0.f);
                }
#pragma unroll
                for (int t = 0; t < 5; ++t)
                    acc[t] = __builtin_amdgcn_mfma_f32_16x16x32_bf16(af, b[t][9], acc[t], 0, 0, 0);
            }
        } else {
            const __bf16* Ab = (const __bf16*)Ap + (size_t)(mt * 16 + r) * KP + q * 8;
#pragma unroll
            for (int ks = 0; ks < 10; ++ks) {
                bf16x8 af = *(const bf16x8*)(Ab + ks * 32);
#pragma unroll
                for (int t = 0; t < 5; ++t)
                    acc[t] = __builtin_amdgcn_mfma_f32_16x16x32_bf16(af, b[t][ks], acc[t], 0, 0, 0);
            }
        }
#pragma unroll
        for (int t = 0; t < 5; ++t) {
            const int n = (w * 5 + t) * 16 + r;
#pragma unroll
            for (int j = 0; j < 4; ++j) {
                const int m = mt * 16 + q * 4 + j;
                unsigned int p8 = (unsigned int)__builtin_amdgcn_cvt_pk_fp8_f32(
                    acc[t][j], acc[t][j], 0, false);
                G[(size_t)m * KP + n] = (unsigned char)(p8 & 0xffu);
            }
        }
    }
}

// ---------------- F2: gemm1(otf W1) 0..255 | bucket 256..880 | convW2 881..930 ----------------

__global__ __launch_bounds__(256, 1) void fused2_kernel(const float* __restrict__ A,
                                                        const float* __restrict__ W1,
                                                        const float* __restrict__ W2,
                                                        __bf16* __restrict__ W2b,
                                                        unsigned char* __restrict__ G,
                                                        const int* __restrict__ src,
                                                        const int* __restrict__ dst,
                                                        int* __restrict__ cnt,
                                                        int* __restrict__ bucket) {
    if (blockIdx.x >= GEMMB + BUCKB) {
        const int t = (blockIdx.x - GEMMB - BUCKB) * 256 + threadIdx.x;   // 0..12799
        const int n = t / (KP / 8);
        const int k0 = (t % (KP / 8)) * 8;
        bf16x8 v2;
#pragma unroll
        for (int i = 0; i < 8; ++i) {
            const int k = k0 + i;
            const bool in = (n < DD) && (k < DD);
            v2[i] = (__bf16)(in ? W2[n * DD + k] : 0.f);
        }
        *(bf16x8*)(W2b + (size_t)n * KP + k0) = v2;
        return;
    }
    if (blockIdx.x >= GEMMB) {
        int e = (blockIdx.x - GEMMB) * 256 + threadIdx.x;
        if (e < NE) {
            int d = dst[e];
            int pos = atomicAdd(&cnt[d], 1);
            if (pos < CAP) bucket[d * CAP + pos] = src[e];
        }
        return;
    }
    gemm_body<true, true>(blockIdx.x, GEMMB, (const void*)A, (const void*)W1, G);
}

// ---------------- K4: gemm2 (bf16 A, bf16 W2b) ----------------

__global__ __launch_bounds__(256, 1) void gemm2_kernel(const __bf16* __restrict__ A,
                                                       const __bf16* __restrict__ Wb,
                                                       unsigned char* __restrict__ G) {
    gemm_body<false, false>(blockIdx.x, GEMMB, (const void*)A, (const void*)Wb, G);
}

// ---------------- aggregation over fp8 G + bias + relu; 2 nodes x 2 waves ----------------
// REPS>1: DIAGNOSTIC — full recompute + idempotent store per rep (R11 pattern, no early
// returns across reps). Makes agg visible in top-5 with counters.

template <bool LAST, int REPS>
__global__ __launch_bounds__(256) void agg_kernel(const unsigned char* __restrict__ G,
                                                  const float* __restrict__ bias,
                                                  void* __restrict__ outp,
                                                  const int* __restrict__ cnt,
                                                  const int* __restrict__ bucket) {
    __shared__ float part[2][KP];
    const int w = threadIdx.x >> 6;        // 0..3
    const int lane = threadIdx.x & 63;
    const int nsub = w >> 1;               // node slot in block
    const int half = w & 1;                // 0: self + first half; 1: second half
    const int node = blockIdx.x * 2 + nsub;   // grid 5000 x 2 = 10000 exactly
    const bool act = lane < (KP / 8);      // 40 lanes x 8 fp8 = 320 B row
    const uint2* hv = (const uint2*)G;     // row stride KP/8 = 40 uint2

    const int c = min(cnt[node], CAP);
    const int h0 = c >> 1;
    const int myBase = node * CAP + (half ? h0 : 0);
    const int myCnt = half ? (c - h0) : h0;

    for (int rep = 0; rep < REPS; ++rep) {
        float acc[8] = {};
        auto addv = [&](uint2 v) {
            f32x2 a0 = __builtin_amdgcn_cvt_pk_f32_fp8(v.x, false);
            f32x2 a1 = __builtin_amdgcn_cvt_pk_f32_fp8(v.x, true);
            f32x2 a2 = __builtin_amdgcn_cvt_pk_f32_fp8(v.y, false);
            f32x2 a3 = __builtin_amdgcn_cvt_pk_f32_fp8(v.y, true);
            acc[0] += a0[0]; acc[1] += a0[1]; acc[2] += a1[0]; acc[3] += a1[1];
            acc[4] += a2[0]; acc[5] += a2[1]; acc[6] += a3[0]; acc[7] += a3[1];
        };

        if (!half && act) addv(hv[(size_t)node * (KP / 8) + lane]);   // self-loop

        int idx = 0;
        if (lane < myCnt) idx = bucket[myBase + lane];
        int j = 0;
        for (; j + 4 <= myCnt; j += 4) {       // 4 gathers in flight
            int n0 = __shfl(idx, j),     n1 = __shfl(idx, j + 1);
            int n2 = __shfl(idx, j + 2), n3 = __shfl(idx, j + 3);
            if (act) {
                uint2 v0 = hv[(size_t)n0 * (KP / 8) + lane];
                uint2 v1 = hv[(size_t)n1 * (KP / 8) + lane];
                uint2 v2 = hv[(size_t)n2 * (KP / 8) + lane];
                uint2 v3 = hv[(size_t)n3 * (KP / 8) + lane];
                addv(v0); addv(v1); addv(v2); addv(v3);
            }
        }
        for (; j < myCnt; ++j) {
            int nb = __shfl(idx, j);
            if (act) addv(hv[(size_t)nb * (KP / 8) + lane]);
        }

        // combine wave pair through LDS (no early returns: all threads stay for all reps)
        if (half && act) {
            *(f32x4*)&part[nsub][lane * 8]     = (f32x4){acc[0], acc[1], acc[2], acc[3]};
            *(f32x4*)&part[nsub][lane * 8 + 4] = (f32x4){acc[4], acc[5], acc[6], acc[7]};
        }
        __syncthreads();
        if (!half && act) {
            f32x4 p0 = *(const f32x4*)&part[nsub][lane * 8];
            f32x4 p1 = *(const f32x4*)&part[nsub][lane * 8 + 4];
#pragma unroll
            for (int i = 0; i < 4; ++i) { acc[i] += p0[i]; acc[4 + i] += p1[i]; }

            const int c0 = lane * 8;
            if (LAST) {
                float* out = (float*)outp + (size_t)node * DD + c0;
#pragma unroll
                for (int i = 0; i < 8; ++i) {
                    int n = c0 + i;
                    if (n < DD) {
                        float v = acc[i] + bias[n];
                        out[i] = v > 0.f ? v : 0.f;
                    }
                }
            } else {
                bf16x8 o;
#pragma unroll
                for (int i = 0; i < 8; ++i) {
                    int n = c0 + i;
                    float v = (n < DD) ? acc[i] + bias[n] : 0.f;
                    v = v > 0.f ? v : 0.f;
                    o[i] = (__bf16)v;
                }
                *(bf16x8*)((__bf16*)outp + (size_t)node * KP + c0) = o;
            }
        }
        __syncthreads();   // protect part[] before next rep overwrites
    }
}

// ---------------- launch (memset + 4 kernels; agg1 at REPS=4 for diagnosis) ----------------

extern "C" void kernel_launch(void* const* d_in, const int* in_sizes, int n_in,
                              void* d_out, int out_size, void* d_ws, size_t ws_size,
                              hipStream_t stream) {
    const float* features = (const float*)d_in[0];
    const int*   src      = (const int*)d_in[1];
    const int*   dst      = (const int*)d_in[2];
    const float* W1       = (const float*)d_in[3];
    const float* b1       = (const float*)d_in[4];
    const float* W2       = (const float*)d_in[5];
    const float* b2       = (const float*)d_in[6];
    float* out = (float*)d_out;

    char* ws = (char*)d_ws;
    size_t off = 0;
    auto alloc = [&](size_t bytes) -> void* {
        void* p = ws + off;
        off += (bytes + 255) & ~(size_t)255;
        return p;
    };
    int*    cnt    = (int*)alloc(NN * sizeof(int));
    int*    bucket = (int*)alloc((size_t)NN * CAP * sizeof(int));
    __bf16* W2b    = (__bf16*)alloc((size_t)NPAD * KP * sizeof(__bf16));
    unsigned char* Gbuf = (unsigned char*)alloc((size_t)NN * KP);   // fp8 G, 3.2 MB
    __bf16* h1b    = (__bf16*)alloc((size_t)NN * KP * sizeof(__bf16));
    (void)ws_size; (void)in_sizes; (void)n_in; (void)out_size;

    // N1: zero cnt
    hipMemsetAsync(cnt, 0, NN * sizeof(int), stream);
    // N2: gemm1 (otf W1) || bucket fill || convW2
    hipLaunchKernelGGL(fused2_kernel, dim3(GEMMB + BUCKB + CONVB), dim3(256), 0, stream,
                       features, W1, W2, W2b, Gbuf, src, dst, cnt, bucket);
    // N3: h1 = relu(agg(G1) + b1)  — DIAGNOSTIC REPS=4
    hipLaunchKernelGGL((agg_kernel<false, 4>), dim3(NN / 2), dim3(256), 0, stream,
                       Gbuf, b1, (void*)h1b, cnt, bucket);
    // N4: G2 = fp8(h1 . W2^T)
    hipLaunchKernelGGL(gemm2_kernel, dim3(GEMMB), dim3(256), 0, stream, h1b, W2b, Gbuf);
    // N5: out = relu(agg(G2) + b2)
    hipLaunchKernelGGL((agg_kernel<true, 1>), dim3(NN / 2), dim3(256), 0, stream,
                       Gbuf, b2, (void*)out, cnt, bucket);
}

// Round 18
// 83.065 us; speedup vs baseline: 1.4727x; 1.4727x over previous
//
#include <hip/hip_runtime.h>
#include <hip/hip_bf16.h>
#include <cstdint>
#include <cstddef>

#define NN 10000
#define NE 160000
#define DD 300
#define KP 320      // K padded to 10 MFMA steps of 32
#define NPAD 320    // W rows padded to 20 tiles of 16
#define MTILES 625  // NN/16
#define CAP 64      // bucket capacity per node (max degree ~35 for this graph)
#define GEMMB 256   // gemm blocks inside the fused kernel
#define BUCKB 625   // bucket blocks (625*256 = NE exactly)
#define CONVB 50    // W2-conversion blocks (50*256*8 = NPAD*KP exactly)

using bf16x8 = __attribute__((ext_vector_type(8))) __bf16;
using f32x4  = __attribute__((ext_vector_type(4))) float;
using f32x2  = __attribute__((ext_vector_type(2))) float;

// ---------------- branch-free masked on-the-fly W row -> 10 bf16x8 frags ----------------

__device__ __forceinline__ void load_b_otf(const float* __restrict__ W, int n, int q,
                                           bf16x8* __restrict__ b) {
    const int nc = (n < DD) ? n : 0;
    const float rowm = (n < DD) ? 1.f : 0.f;
    const float* base = W + nc * DD + q * 8;
#pragma unroll
    for (int ks = 0; ks < 10; ++ks) {
        const int k0 = q * 8 + ks * 32;
        f32x4 lo = *(const f32x4*)(base + ks * 32);
        f32x4 hi = *(const f32x4*)(base + ks * 32 + 4);
        bf16x8 bf;
#pragma unroll
        for (int j = 0; j < 4; ++j) {
            const float ml = (k0 + j < DD) ? rowm : 0.f;
            const float mh = (k0 + 4 + j < DD) ? rowm : 0.f;
            bf[j]     = (__bf16)(lo[j] * ml);
            bf[4 + j] = (__bf16)(hi[j] * mh);
        }
        b[ks] = bf;
    }
}

// ---------------- shared GEMM body: G[m][n] = fp8(sum_k A[m][k]*W[n][k]) ----------------

template <bool F32IN, bool OTFW>
__device__ __forceinline__ void gemm_body(int bid, int gstride,
                                          const void* __restrict__ Ap,
                                          const void* __restrict__ Wsrc,
                                          unsigned char* __restrict__ G) {
    const int w = threadIdx.x >> 6;
    const int lane = threadIdx.x & 63;
    const int r = lane & 15;    // A row-in-tile / B col / D col
    const int q = lane >> 4;    // k-block select / D row-block

    bf16x8 b[5][10];
    if constexpr (OTFW) {
        const float* W = (const float*)Wsrc;
#pragma unroll
        for (int t = 0; t < 5; ++t)
            load_b_otf(W, (w * 5 + t) * 16 + r, q, b[t]);
    } else {
        const __bf16* Wb = (const __bf16*)Wsrc;
        const __bf16* Bb = Wb + (size_t)r * KP + q * 8;
#pragma unroll
        for (int t = 0; t < 5; ++t) {
            const __bf16* Bt = Bb + (size_t)(w * 5 + t) * 16 * KP;
#pragma unroll
            for (int ks = 0; ks < 10; ++ks)
                b[t][ks] = *(const bf16x8*)(Bt + ks * 32);
        }
    }

    for (int mt = bid; mt < MTILES; mt += gstride) {
        f32x4 acc[5] = {};
        if constexpr (F32IN) {
            const float* Ab = (const float*)Ap + (size_t)(mt * 16 + r) * DD + q * 8;
#pragma unroll
            for (int ks = 0; ks < 9; ++ks) {   // k0+7 <= 287 < 300: full vectors
                f32x4 lo = *(const f32x4*)(Ab + ks * 32);
                f32x4 hi = *(const f32x4*)(Ab + ks * 32 + 4);
                bf16x8 af;
#pragma unroll
                for (int j = 0; j < 4; ++j) { af[j] = (__bf16)lo[j]; af[4 + j] = (__bf16)hi[j]; }
#pragma unroll
                for (int t = 0; t < 5; ++t)
                    acc[t] = __builtin_amdgcn_mfma_f32_16x16x32_bf16(af, b[t][ks], acc[t], 0, 0, 0);
            }
            {   // ks = 9: k = 288 + q*8 + j, guard k < 300
                bf16x8 af;
#pragma unroll
                for (int j = 0; j < 8; ++j) {
                    int k = 288 + q * 8 + j;
                    af[j] = (__bf16)((k < DD) ? Ab[288 + j] : 0.f);
                }
#pragma unroll
                for (int t = 0; t < 5; ++t)
                    acc[t] = __builtin_amdgcn_mfma_f32_16x16x32_bf16(af, b[t][9], acc[t], 0, 0, 0);
            }
        } else {
            const __bf16* Ab = (const __bf16*)Ap + (size_t)(mt * 16 + r) * KP + q * 8;
#pragma unroll
            for (int ks = 0; ks < 10; ++ks) {
                bf16x8 af = *(const bf16x8*)(Ab + ks * 32);
#pragma unroll
                for (int t = 0; t < 5; ++t)
                    acc[t] = __builtin_amdgcn_mfma_f32_16x16x32_bf16(af, b[t][ks], acc[t], 0, 0, 0);
            }
        }
#pragma unroll
        for (int t = 0; t < 5; ++t) {
            const int n = (w * 5 + t) * 16 + r;
#pragma unroll
            for (int j = 0; j < 4; ++j) {
                const int m = mt * 16 + q * 4 + j;
                unsigned int p8 = (unsigned int)__builtin_amdgcn_cvt_pk_fp8_f32(
                    acc[t][j], acc[t][j], 0, false);
                G[(size_t)m * KP + n] = (unsigned char)(p8 & 0xffu);
            }
        }
    }
}

// ---------------- F2: gemm1(otf W1) 0..255 | bucket 256..880 | convW2 881..930 ----------------

__global__ __launch_bounds__(256, 1) void fused2_kernel(const float* __restrict__ A,
                                                        const float* __restrict__ W1,
                                                        const float* __restrict__ W2,
                                                        __bf16* __restrict__ W2b,
                                                        unsigned char* __restrict__ G,
                                                        const int* __restrict__ src,
                                                        const int* __restrict__ dst,
                                                        int* __restrict__ cnt,
                                                        int* __restrict__ bucket) {
    if (blockIdx.x >= GEMMB + BUCKB) {
        const int t = (blockIdx.x - GEMMB - BUCKB) * 256 + threadIdx.x;   // 0..12799
        const int n = t / (KP / 8);
        const int k0 = (t % (KP / 8)) * 8;
        bf16x8 v2;
#pragma unroll
        for (int i = 0; i < 8; ++i) {
            const int k = k0 + i;
            const bool in = (n < DD) && (k < DD);
            v2[i] = (__bf16)(in ? W2[n * DD + k] : 0.f);
        }
        *(bf16x8*)(W2b + (size_t)n * KP + k0) = v2;
        return;
    }
    if (blockIdx.x >= GEMMB) {
        int e = (blockIdx.x - GEMMB) * 256 + threadIdx.x;
        if (e < NE) {
            int d = dst[e];
            int pos = atomicAdd(&cnt[d], 1);
            if (pos < CAP) bucket[d * CAP + pos] = src[e];
        }
        return;
    }
    gemm_body<true, true>(blockIdx.x, GEMMB, (const void*)A, (const void*)W1, G);
}

// ---------------- K4: gemm2 (bf16 A, bf16 W2b) ----------------

__global__ __launch_bounds__(256, 1) void gemm2_kernel(const __bf16* __restrict__ A,
                                                       const __bf16* __restrict__ Wb,
                                                       unsigned char* __restrict__ G) {
    gemm_body<false, false>(blockIdx.x, GEMMB, (const void*)A, (const void*)Wb, G);
}

// ---------------- aggregation over fp8 G + bias + relu; 2 nodes x 2 waves ----------------
// Latency-chain-optimized (R17 diagnosis: 2/3 of agg time = exposed L2-hit latency):
//  - static parity partition of bucket slots (half h owns slots h, h+2, ...) so the
//    idx load needs no count -> cnt, idx, self-row loads all issue in parallel;
//  - 8-deep gather batches (8 shfl -> 8 loads in flight -> 8 addv) + 4/2/1 tail:
//    typical myCnt ~8-9 = ONE latency round instead of three.
// LAST: f32 [NN][DD] out; else bf16 [NN][KP] out with zero pads.

template <bool LAST>
__global__ __launch_bounds__(256) void agg_kernel(const unsigned char* __restrict__ G,
                                                  const float* __restrict__ bias,
                                                  void* __restrict__ outp,
                                                  const int* __restrict__ cnt,
                                                  const int* __restrict__ bucket) {
    __shared__ float part[2][KP + 8];      // +8 pad: breaks 4-way LDS write conflict
    const int w = threadIdx.x >> 6;        // 0..3
    const int lane = threadIdx.x & 63;
    const int nsub = w >> 1;               // node slot in block
    const int half = w & 1;                // slot parity owned by this wave
    const int node = blockIdx.x * 2 + nsub;   // grid 5000 x 2 = 10000 exactly
    const bool act = lane < (KP / 8);      // 40 lanes x 8 fp8 = 320 B row
    const uint2* hv = (const uint2*)G;     // row stride KP/8 = 40 uint2

    // --- three independent loads, all issued before any dependency ---
    int idx = 0;
    if (lane < 32) idx = bucket[node * CAP + 2 * lane + half];   // no cnt dependency
    const int c = min(cnt[node], CAP);
    const int myCnt = (c - half + 1) >> 1;   // #slots of parity `half` below c

    float acc[8] = {};
    auto addv = [&](uint2 v) {
        f32x2 a0 = __builtin_amdgcn_cvt_pk_f32_fp8(v.x, false);
        f32x2 a1 = __builtin_amdgcn_cvt_pk_f32_fp8(v.x, true);
        f32x2 a2 = __builtin_amdgcn_cvt_pk_f32_fp8(v.y, false);
        f32x2 a3 = __builtin_amdgcn_cvt_pk_f32_fp8(v.y, true);
        acc[0] += a0[0]; acc[1] += a0[1]; acc[2] += a1[0]; acc[3] += a1[1];
        acc[4] += a2[0]; acc[5] += a2[1]; acc[6] += a3[0]; acc[7] += a3[1];
    };

    if (!half && act) addv(hv[(size_t)node * (KP / 8) + lane]);   // self-loop (independent)

    int j = 0;
    for (; j + 8 <= myCnt; j += 8) {       // 8 gathers in flight
        int nb[8];
#pragma unroll
        for (int r = 0; r < 8; ++r) nb[r] = __shfl(idx, j + r);
        if (act) {
            uint2 v[8];
#pragma unroll
            for (int r = 0; r < 8; ++r) v[r] = hv[(size_t)nb[r] * (KP / 8) + lane];
#pragma unroll
            for (int r = 0; r < 8; ++r) addv(v[r]);
        }
    }
    if (j + 4 <= myCnt) {                  // 4-tail
        int nb[4];
#pragma unroll
        for (int r = 0; r < 4; ++r) nb[r] = __shfl(idx, j + r);
        if (act) {
            uint2 v[4];
#pragma unroll
            for (int r = 0; r < 4; ++r) v[r] = hv[(size_t)nb[r] * (KP / 8) + lane];
#pragma unroll
            for (int r = 0; r < 4; ++r) addv(v[r]);
        }
        j += 4;
    }
    if (j + 2 <= myCnt) {                  // 2-tail
        int n0 = __shfl(idx, j), n1 = __shfl(idx, j + 1);
        if (act) {
            uint2 v0 = hv[(size_t)n0 * (KP / 8) + lane];
            uint2 v1 = hv[(size_t)n1 * (KP / 8) + lane];
            addv(v0); addv(v1);
        }
        j += 2;
    }
    if (j < myCnt) {                       // 1-tail
        int nb = __shfl(idx, j);
        if (act) addv(hv[(size_t)nb * (KP / 8) + lane]);
    }

    // combine wave pair through LDS
    if (half && act) {
        *(f32x4*)&part[nsub][lane * 8]     = (f32x4){acc[0], acc[1], acc[2], acc[3]};
        *(f32x4*)&part[nsub][lane * 8 + 4] = (f32x4){acc[4], acc[5], acc[6], acc[7]};
    }
    __syncthreads();
    if (half || !act) return;

    f32x4 p0 = *(const f32x4*)&part[nsub][lane * 8];
    f32x4 p1 = *(const f32x4*)&part[nsub][lane * 8 + 4];
#pragma unroll
    for (int i = 0; i < 4; ++i) { acc[i] += p0[i]; acc[4 + i] += p1[i]; }

    const int c0 = lane * 8;
    if (LAST) {
        float* out = (float*)outp + (size_t)node * DD + c0;
#pragma unroll
        for (int i = 0; i < 8; ++i) {
            int n = c0 + i;
            if (n < DD) {
                float v = acc[i] + bias[n];
                out[i] = v > 0.f ? v : 0.f;
            }
        }
    } else {
        bf16x8 o;
#pragma unroll
        for (int i = 0; i < 8; ++i) {
            int n = c0 + i;
            float v = (n < DD) ? acc[i] + bias[n] : 0.f;
            v = v > 0.f ? v : 0.f;
            o[i] = (__bf16)v;
        }
        *(bf16x8*)((__bf16*)outp + (size_t)node * KP + c0) = o;
    }
}

// ---------------- launch (memset + 4 kernels) ----------------

extern "C" void kernel_launch(void* const* d_in, const int* in_sizes, int n_in,
                              void* d_out, int out_size, void* d_ws, size_t ws_size,
                              hipStream_t stream) {
    const float* features = (const float*)d_in[0];
    const int*   src      = (const int*)d_in[1];
    const int*   dst      = (const int*)d_in[2];
    const float* W1       = (const float*)d_in[3];
    const float* b1       = (const float*)d_in[4];
    const float* W2       = (const float*)d_in[5];
    const float* b2       = (const float*)d_in[6];
    float* out = (float*)d_out;

    char* ws = (char*)d_ws;
    size_t off = 0;
    auto alloc = [&](size_t bytes) -> void* {
        void* p = ws + off;
        off += (bytes + 255) & ~(size_t)255;
        return p;
    };
    int*    cnt    = (int*)alloc(NN * sizeof(int));
    int*    bucket = (int*)alloc((size_t)NN * CAP * sizeof(int));
    __bf16* W2b    = (__bf16*)alloc((size_t)NPAD * KP * sizeof(__bf16));
    unsigned char* Gbuf = (unsigned char*)alloc((size_t)NN * KP);   // fp8 G, 3.2 MB (L2-resident)
    __bf16* h1b    = (__bf16*)alloc((size_t)NN * KP * sizeof(__bf16));
    (void)ws_size; (void)in_sizes; (void)n_in; (void)out_size;

    // N1: zero cnt
    hipMemsetAsync(cnt, 0, NN * sizeof(int), stream);
    // N2: gemm1 (otf W1) || bucket fill || convW2
    hipLaunchKernelGGL(fused2_kernel, dim3(GEMMB + BUCKB + CONVB), dim3(256), 0, stream,
                       features, W1, W2, W2b, Gbuf, src, dst, cnt, bucket);
    // N3: h1 = relu(agg(G1) + b1)  (bf16 out)
    hipLaunchKernelGGL((agg_kernel<false>), dim3(NN / 2), dim3(256), 0, stream,
                       Gbuf, b1, (void*)h1b, cnt, bucket);
    // N4: G2 = fp8(h1 . W2^T)
    hipLaunchKernelGGL(gemm2_kernel, dim3(GEMMB), dim3(256), 0, stream, h1b, W2b, Gbuf);
    // N5: out = relu(agg(G2) + b2)  (f32 out)
    hipLaunchKernelGGL((agg_kernel<true>), dim3(NN / 2), dim3(256), 0, stream,
                       Gbuf, b2, (void*)out, cnt, bucket);
}